// Round 4
// baseline (222.732 us; speedup 1.0000x reference)
//
#include <hip/hip_runtime.h>

#define TT 128
#define BB 512
#define DD 512
#define HH 512
#define CC 32
#define NQ 10
#define GC 128      // 4 gates * 32 centres
#define DH 1024     // D + H
#define CHUNK 8
#define NCHUNK (TT / CHUNK)

typedef __fp16 h2 __attribute__((ext_vector_type(2)));
typedef __fp16 h4 __attribute__((ext_vector_type(4)));
typedef __fp16 h8 __attribute__((ext_vector_type(8)));
typedef float f4 __attribute__((ext_vector_type(4)));

__device__ __forceinline__ float rcpf(float x) {
    return __builtin_amdgcn_rcpf(x);
}
__device__ __forceinline__ float sigmf(float x) {
    return rcpf(1.f + __expf(-x));
}
__device__ __forceinline__ float tanhfast(float x) {
    // tanh(x) = 1 - 2/(e^{2x}+1); saturates correctly at +-inf
    return 1.f - 2.f * rcpf(1.f + __expf(2.f * x));
}

__global__ __launch_bounds__(512, 4) void qlstm_kernel(
    const float* __restrict__ inputs,   // [T][B][D]
    const float* __restrict__ centres,  // [4][C][DH]
    const float* __restrict__ lin_w,    // [4][H][C]
    const float* __restrict__ lin_b,    // [4][H]
    float* __restrict__ out)            // outputs [T][B][H] | h [B][H] | c [B][H]
{
    // 74 KB total -> 2 blocks/CU
    __shared__ __fp16 Klds[TT * GC];          // 32 KiB, XOR-swizzled rows
    __shared__ unsigned pre_fi[CHUNK * HH];   // 16 KiB: gates f,i packed h2
    __shared__ unsigned pre_go[CHUNK * HH];   // 16 KiB: gates g,o packed h2
    __shared__ float xs[TT * NQ];             // 5 KiB
    __shared__ float cs[GC * NQ];             // 5 KiB

    const int b = blockIdx.x;
    const int tid = threadIdx.x;
    const int lane = tid & 63;
    const int w = tid >> 6;       // wave id 0..7; wave w owns h in [w*64, w*64+64)
    const int q = lane >> 4;      // 0..3
    const int c16 = lane & 15;

    // ---- B fragments (weights) in registers: lane holds col n=c16, k=q*8+e ----
    h8 bfr[16];       // [g*4 + j], j = N-subtile (hcol = (w*4+j)*16 + c16)
    float biasv[16];  // [g*4 + j]
    {
        const int c0 = q * 8;
        #pragma unroll
        for (int g = 0; g < 4; ++g) {
            #pragma unroll
            for (int j = 0; j < 4; ++j) {
                const int hcol = (w * 4 + j) * 16 + c16;
                const float* wp = lin_w + (((size_t)g * HH + hcol) * CC + c0);
                f4 lo = *(const f4*)wp;
                f4 hi = *(const f4*)(wp + 4);
                h2 p0 = __builtin_amdgcn_cvt_pkrtz(lo.x, lo.y);
                h2 p1 = __builtin_amdgcn_cvt_pkrtz(lo.z, lo.w);
                h2 p2 = __builtin_amdgcn_cvt_pkrtz(hi.x, hi.y);
                h2 p3 = __builtin_amdgcn_cvt_pkrtz(hi.z, hi.w);
                h8 bb = { p0.x, p0.y, p1.x, p1.y, p2.x, p2.y, p3.x, p3.y };
                bfr[g * 4 + j] = bb;
                biasv[g * 4 + j] = lin_b[g * HH + hcol];
            }
        }
    }

    // ---- stage x (first 10 feats per t) and centres (first 10 cols) ----
    for (int idx = tid; idx < TT * NQ; idx += 512) {
        int t = idx / NQ, qq = idx - t * NQ;
        xs[idx] = inputs[((size_t)t * BB + b) * DD + qq];
    }
    for (int idx = tid; idx < GC * NQ; idx += 512) {
        int gc = idx / NQ, qq = idx - gc * NQ;
        cs[idx] = centres[(size_t)gc * DH + qq];
    }
    __syncthreads();

    // ---- Phase A: K[t][gc] -> LDS f16, 4 values per item, swizzled write ----
    // byte addr = (t*256 + gc*2) ^ ((t&7)<<4); 8B-aligned writes stay aligned.
    for (int p = 0; p < 8; ++p) {
        int idx = tid + p * 512;          // 4096 items of 4 gc each
        int t = idx >> 5, gc0 = (idx & 31) * 4;
        const float* xr = &xs[t * NQ];
        float pv[4];
        #pragma unroll
        for (int u = 0; u < 4; ++u) {
            const float* cr = &cs[(gc0 + u) * NQ];
            float pr = 1.f;
            #pragma unroll
            for (int qq = 0; qq < NQ; ++qq)
                pr *= fabsf(__cosf(0.5f * (xr[qq] - cr[qq])));
            pv[u] = pr;
        }
        h2 lo2 = __builtin_amdgcn_cvt_pkrtz(pv[0], pv[1]);
        h2 hi2 = __builtin_amdgcn_cvt_pkrtz(pv[2], pv[3]);
        h4 kk = { lo2.x, lo2.y, hi2.x, hi2.y };
        int byteo = (t * 256 + gc0 * 2) ^ ((t & 7) << 4);
        *(h4*)((char*)Klds + byteo) = kk;
    }
    __syncthreads();

    // ---- per 8-t chunk: MFMA pre-activations (bias in C), then recurrence ----
    float cstate = 0.f, hstate = 0.f;
    float* op = out + (size_t)b * HH + tid;
    const int tlo = c16 & 7;      // duplicated A rows: t = ct*8 + tlo

    for (int ct = 0; ct < NCHUNK; ++ct) {
        const int arow = ct * CHUNK + tlo;
        // A-fragment: row m = c16 (dup pairs), k = q*8+e; swizzled b128 read
        h8 afr[4];
        #pragma unroll
        for (int g = 0; g < 4; ++g)
            afr[g] = *(const h8*)((const char*)Klds +
                     ((arow * 256 + g * 64 + q * 16) ^ ((arow & 7) << 4)));

        #pragma unroll
        for (int j = 0; j < 4; ++j) {
            f4 c0 = { biasv[0*4+j], biasv[0*4+j], biasv[0*4+j], biasv[0*4+j] };
            f4 c1 = { biasv[1*4+j], biasv[1*4+j], biasv[1*4+j], biasv[1*4+j] };
            f4 c2 = { biasv[2*4+j], biasv[2*4+j], biasv[2*4+j], biasv[2*4+j] };
            f4 c3 = { biasv[3*4+j], biasv[3*4+j], biasv[3*4+j], biasv[3*4+j] };
            f4 a0 = __builtin_amdgcn_mfma_f32_16x16x32_f16(afr[0], bfr[0*4+j], c0, 0, 0, 0);
            f4 a1 = __builtin_amdgcn_mfma_f32_16x16x32_f16(afr[1], bfr[1*4+j], c1, 0, 0, 0);
            f4 a2 = __builtin_amdgcn_mfma_f32_16x16x32_f16(afr[2], bfr[2*4+j], c2, 0, 0, 0);
            f4 a3 = __builtin_amdgcn_mfma_f32_16x16x32_f16(afr[3], bfr[3*4+j], c3, 0, 0, 0);
            // D: col = c16 (h), row = q*4+r (t_local); rows 8-15 are dups, skip
            if (q < 2) {
                const int hcol = (w * 4 + j) * 16 + c16;
                #pragma unroll
                for (int r = 0; r < 4; ++r) {
                    const int tl = q * 4 + r;                 // 0..7
                    h2 p01 = __builtin_amdgcn_cvt_pkrtz(a0[r], a1[r]);
                    h2 p23 = __builtin_amdgcn_cvt_pkrtz(a2[r], a3[r]);
                    const int colw = hcol ^ (q << 4);         // bank-group spread
                    pre_fi[tl * HH + colw] = *(unsigned*)&p01;
                    pre_go[tl * HH + colw] = *(unsigned*)&p23;
                }
            }
        }
        __syncthreads();

        // recurrence: thread = h, 8 steps, 2 ds_read_b32 each (conflict-free)
        #pragma unroll
        for (int tl = 0; tl < CHUNK; ++tl) {
            const int colr = tid ^ ((tl & 4) << 2);           // ((tl>>2)&1)<<4
            unsigned ufi = pre_fi[tl * HH + colr];
            unsigned ugo = pre_go[tl * HH + colr];
            h2 vfi = *(h2*)&ufi;
            h2 vgo = *(h2*)&ugo;
            float fg = sigmf((float)vfi.x);
            float ig = sigmf((float)vfi.y);
            float gg = tanhfast((float)vgo.x);
            float og = sigmf((float)vgo.y);
            cstate = fg * cstate + ig * gg;
            hstate = og * tanhfast(cstate);
            op[(size_t)(ct * CHUNK + tl) * (BB * HH)] = hstate;
        }
        __syncthreads();
    }

    float* hout = out + (size_t)TT * BB * HH;
    float* cout = hout + (size_t)BB * HH;
    hout[(size_t)b * HH + tid] = hstate;
    cout[(size_t)b * HH + tid] = cstate;
}

extern "C" void kernel_launch(void* const* d_in, const int* in_sizes, int n_in,
                              void* d_out, int out_size, void* d_ws, size_t ws_size,
                              hipStream_t stream) {
    const float* inputs  = (const float*)d_in[0];
    const float* centres = (const float*)d_in[1];
    const float* lin_w   = (const float*)d_in[2];
    const float* lin_b   = (const float*)d_in[3];
    float* out = (float*)d_out;

    qlstm_kernel<<<dim3(BB), dim3(512), 0, stream>>>(inputs, centres, lin_w, lin_b, out);
}

// Round 5
// 98.404 us; speedup vs baseline: 2.2634x; 2.2634x over previous
//
#include <hip/hip_runtime.h>

#define TT 128
#define BB 512
#define DD 512
#define HH 512
#define CC 32
#define NQ 10
#define GC 128      // 4 gates * 32 centres
#define DH 1024     // D + H
#define CHUNK 8
#define NCHUNK (TT / CHUNK)

typedef __fp16 h2 __attribute__((ext_vector_type(2)));
typedef __fp16 h4 __attribute__((ext_vector_type(4)));
typedef __fp16 h8 __attribute__((ext_vector_type(8)));
typedef float f4 __attribute__((ext_vector_type(4)));

__device__ __forceinline__ float rcpf(float x) {
    return __builtin_amdgcn_rcpf(x);
}
__device__ __forceinline__ float sigmf(float x) {
    return rcpf(1.f + __expf(-x));
}
__device__ __forceinline__ float tanhfast(float x) {
    // tanh(x) = 1 - 2/(e^{2x}+1); saturates correctly at +-inf
    return 1.f - 2.f * rcpf(1.f + __expf(2.f * x));
}

__global__ __launch_bounds__(512, 2) void qlstm_kernel(
    const float* __restrict__ inputs,   // [T][B][D]
    const float* __restrict__ centres,  // [4][C][DH]
    const float* __restrict__ lin_w,    // [4][H][C]
    const float* __restrict__ lin_b,    // [4][H]
    float* __restrict__ out)            // outputs [T][B][H] | h [B][H] | c [B][H]
{
    // 74 KB total -> 2 blocks/CU
    __shared__ __fp16 Klds[TT * GC];          // 32 KiB, XOR-swizzled rows
    __shared__ unsigned pre_fi[CHUNK * HH];   // 16 KiB: gates f,i packed h2 (wave-private cols)
    __shared__ unsigned pre_go[CHUNK * HH];   // 16 KiB: gates g,o packed h2 (wave-private cols)
    __shared__ float xs[TT * NQ];             // 5 KiB
    __shared__ float cs[GC * NQ];             // 5 KiB

    const int b = blockIdx.x;
    const int tid = threadIdx.x;
    const int lane = tid & 63;
    const int w = tid >> 6;       // wave id 0..7; wave w owns h in [w*64, w*64+64)
    const int q = lane >> 4;      // 0..3
    const int c16 = lane & 15;

    // ---- B fragments (weights) in registers: lane holds col n=c16, k=q*8+e ----
    h8 bfr[16];   // [g*4 + j], j = N-subtile (hcol = (w*4+j)*16 + c16)
    {
        const int c0 = q * 8;
        #pragma unroll
        for (int g = 0; g < 4; ++g) {
            #pragma unroll
            for (int j = 0; j < 4; ++j) {
                const int hcol = (w * 4 + j) * 16 + c16;
                const float* wp = lin_w + (((size_t)g * HH + hcol) * CC + c0);
                f4 lo = *(const f4*)wp;
                f4 hi = *(const f4*)(wp + 4);
                h2 p0 = __builtin_amdgcn_cvt_pkrtz(lo.x, lo.y);
                h2 p1 = __builtin_amdgcn_cvt_pkrtz(lo.z, lo.w);
                h2 p2 = __builtin_amdgcn_cvt_pkrtz(hi.x, hi.y);
                h2 p3 = __builtin_amdgcn_cvt_pkrtz(hi.z, hi.w);
                h8 bb = { p0.x, p0.y, p1.x, p1.y, p2.x, p2.y, p3.x, p3.y };
                bfr[g * 4 + j] = bb;
            }
        }
    }

    const float bias0 = lin_b[0 * HH + tid];
    const float bias1 = lin_b[1 * HH + tid];
    const float bias2 = lin_b[2 * HH + tid];
    const float bias3 = lin_b[3 * HH + tid];

    // ---- stage x (first 10 feats per t) and centres (first 10 cols) ----
    for (int idx = tid; idx < TT * NQ; idx += 512) {
        int t = idx / NQ, qq = idx - t * NQ;
        xs[idx] = inputs[((size_t)t * BB + b) * DD + qq];
    }
    for (int idx = tid; idx < GC * NQ; idx += 512) {
        int gc = idx / NQ, qq = idx - gc * NQ;
        cs[idx] = centres[(size_t)gc * DH + qq];
    }
    __syncthreads();

    // ---- Phase A: K[t][gc] -> LDS f16, 4 values per item, swizzled write ----
    // byte addr = (t*256 + gc*2) ^ ((t&7)<<4); 8B-aligned writes stay aligned.
    for (int p = 0; p < 8; ++p) {
        int idx = tid + p * 512;          // 4096 items of 4 gc each
        int t = idx >> 5, gc0 = (idx & 31) * 4;
        const float* xr = &xs[t * NQ];
        float pv[4];
        #pragma unroll
        for (int u = 0; u < 4; ++u) {
            const float* cr = &cs[(gc0 + u) * NQ];
            float pr = 1.f;
            #pragma unroll
            for (int qq = 0; qq < NQ; ++qq)
                pr *= fabsf(__cosf(0.5f * (xr[qq] - cr[qq])));
            pv[u] = pr;
        }
        h2 lo2 = __builtin_amdgcn_cvt_pkrtz(pv[0], pv[1]);
        h2 hi2 = __builtin_amdgcn_cvt_pkrtz(pv[2], pv[3]);
        h4 kk = { lo2.x, lo2.y, hi2.x, hi2.y };
        int byteo = (t * 256 + gc0 * 2) ^ ((t & 7) << 4);
        *(h4*)((char*)Klds + byteo) = kk;
    }
    __syncthreads();   // Klds complete; last barrier in the kernel

    // ---- per 8-t chunk: MFMA pre-activations, then recurrence.            ----
    // ---- pre_* is wave-private (cols [w*64,w*64+64)): NO block barriers.  ----
    float cstate = 0.f, hstate = 0.f;
    float* op = out + (size_t)b * HH + tid;
    const int tlo = c16 & 7;      // duplicated A rows: t = ct*8 + tlo
    const f4 z4 = {0.f, 0.f, 0.f, 0.f};

    for (int ct = 0; ct < NCHUNK; ++ct) {
        const int arow = ct * CHUNK + tlo;
        // A-fragment: row m = c16 (dup pairs), k = q*8+e; swizzled b128 read
        h8 afr[4];
        #pragma unroll
        for (int g = 0; g < 4; ++g)
            afr[g] = *(const h8*)((const char*)Klds +
                     ((arow * 256 + g * 64 + q * 16) ^ ((arow & 7) << 4)));

        #pragma unroll
        for (int j = 0; j < 4; ++j) {
            f4 a0 = __builtin_amdgcn_mfma_f32_16x16x32_f16(afr[0], bfr[0*4+j], z4, 0, 0, 0);
            f4 a1 = __builtin_amdgcn_mfma_f32_16x16x32_f16(afr[1], bfr[1*4+j], z4, 0, 0, 0);
            f4 a2 = __builtin_amdgcn_mfma_f32_16x16x32_f16(afr[2], bfr[2*4+j], z4, 0, 0, 0);
            f4 a3 = __builtin_amdgcn_mfma_f32_16x16x32_f16(afr[3], bfr[3*4+j], z4, 0, 0, 0);
            // D: col = c16 (h), row = q*4+r (t_local); rows 8-15 are dups, skip
            if (q < 2) {
                const int hcol = (w * 4 + j) * 16 + c16;
                #pragma unroll
                for (int r = 0; r < 4; ++r) {
                    const int tl = q * 4 + r;                 // 0..7
                    h2 p01 = __builtin_amdgcn_cvt_pkrtz(a0[r], a1[r]);
                    h2 p23 = __builtin_amdgcn_cvt_pkrtz(a2[r], a3[r]);
                    const int colw = hcol ^ (q << 4);         // bank-group spread
                    pre_fi[tl * HH + colw] = *(unsigned*)&p01;
                    pre_go[tl * HH + colw] = *(unsigned*)&p23;
                }
            }
        }

        // recurrence: thread = h, 8 steps, 2 ds_read_b32 each (conflict-free).
        // Same-wave LDS ordering guarantees the writes above are visible.
        #pragma unroll
        for (int tl = 0; tl < CHUNK; ++tl) {
            const int colr = tid ^ ((tl & 4) << 2);           // ((tl>>2)&1)<<4
            unsigned ufi = pre_fi[tl * HH + colr];
            unsigned ugo = pre_go[tl * HH + colr];
            h2 vfi = *(h2*)&ufi;
            h2 vgo = *(h2*)&ugo;
            float fg = sigmf(bias0 + (float)vfi.x);
            float ig = sigmf(bias1 + (float)vfi.y);
            float gg = tanhfast(bias2 + (float)vgo.x);
            float og = sigmf(bias3 + (float)vgo.y);
            cstate = fg * cstate + ig * gg;
            hstate = og * tanhfast(cstate);
            op[(size_t)(ct * CHUNK + tl) * (BB * HH)] = hstate;
        }
    }

    float* hout = out + (size_t)TT * BB * HH;
    float* cout = hout + (size_t)BB * HH;
    hout[(size_t)b * HH + tid] = hstate;
    cout[(size_t)b * HH + tid] = cstate;
}

extern "C" void kernel_launch(void* const* d_in, const int* in_sizes, int n_in,
                              void* d_out, int out_size, void* d_ws, size_t ws_size,
                              hipStream_t stream) {
    const float* inputs  = (const float*)d_in[0];
    const float* centres = (const float*)d_in[1];
    const float* lin_w   = (const float*)d_in[2];
    const float* lin_b   = (const float*)d_in[3];
    float* out = (float*)d_out;

    qlstm_kernel<<<dim3(BB), dim3(512), 0, stream>>>(inputs, centres, lin_w, lin_b, out);
}

// Round 7
// 84.563 us; speedup vs baseline: 2.6339x; 1.1637x over previous
//
#include <hip/hip_runtime.h>

#define TT 128
#define BB 512
#define DD 512
#define HH 512
#define CC 32
#define NQ 10
#define GC 128      // 4 gates * 32 centres
#define DH 1024     // D + H
#define CHUNK 8
#define NCHUNK (TT / CHUNK)
#define L2E 1.4426950408889634f

typedef __fp16 h2 __attribute__((ext_vector_type(2)));
typedef __fp16 h4 __attribute__((ext_vector_type(4)));
typedef __fp16 h8 __attribute__((ext_vector_type(8)));
typedef float f4 __attribute__((ext_vector_type(4)));

__device__ __forceinline__ float rcpf(float x) {
    return __builtin_amdgcn_rcpf(x);
}
__device__ __forceinline__ float exp2fast(float x) {
#if __has_builtin(__builtin_amdgcn_exp2f)
    return __builtin_amdgcn_exp2f(x);
#else
    return exp2f(x);
#endif
}

__global__ __launch_bounds__(512, 2) void qlstm_kernel(
    const float* __restrict__ inputs,   // [T][B][D]
    const float* __restrict__ centres,  // [4][C][DH]
    const float* __restrict__ lin_w,    // [4][H][C]
    const float* __restrict__ lin_b,    // [4][H]
    float* __restrict__ out)            // outputs [T][B][H] | h [B][H] | c [B][H]
{
    // 76 KB total -> 2 blocks/CU
    __shared__ __fp16 Klds[TT * GC];     // 32 KiB, XOR-swizzled rows
    __shared__ uint2  preB[CHUNK * HH];  // 32 KiB: (f,i | g,o) packed per (tl,h)
    __shared__ float xs[TT * 12];        // 6 KiB: x[t][0:10]/2, padded to 12
    __shared__ float cs[GC * 12];        // 6 KiB: centres[gc][0:10]/2, padded

    const int b = blockIdx.x;
    const int tid = threadIdx.x;
    const int lane = tid & 63;
    const int w = tid >> 6;       // wave id 0..7; wave w owns h in [w*64, w*64+64)
    const int q = lane >> 4;      // 0..3
    const int c16 = lane & 15;

    // ---- B fragments (weights) in registers, scale folded:                ----
    // gates f,i,o: w' = -log2e * w ; gate g: w' = 2*log2e * w.
    h8 bfr[16];   // [g*4 + j], j = N-subtile (hcol = (w*4+j)*16 + c16)
    {
        const int c0 = q * 8;
        #pragma unroll
        for (int g = 0; g < 4; ++g) {
            const float s = (g == 2) ? (2.f * L2E) : (-L2E);
            #pragma unroll
            for (int j = 0; j < 4; ++j) {
                const int hcol = (w * 4 + j) * 16 + c16;
                const float* wp = lin_w + (((size_t)g * HH + hcol) * CC + c0);
                f4 lo = *(const f4*)wp;
                f4 hi = *(const f4*)(wp + 4);
                h2 p0 = __builtin_amdgcn_cvt_pkrtz(s * lo.x, s * lo.y);
                h2 p1 = __builtin_amdgcn_cvt_pkrtz(s * lo.z, s * lo.w);
                h2 p2 = __builtin_amdgcn_cvt_pkrtz(s * hi.x, s * hi.y);
                h2 p3 = __builtin_amdgcn_cvt_pkrtz(s * hi.z, s * hi.w);
                h8 bb = { p0.x, p0.y, p1.x, p1.y, p2.x, p2.y, p3.x, p3.y };
                bfr[g * 4 + j] = bb;
            }
        }
    }

    const float bias0 = -L2E * lin_b[0 * HH + tid];
    const float bias1 = -L2E * lin_b[1 * HH + tid];
    const float bias2 = 2.f * L2E * lin_b[2 * HH + tid];
    const float bias3 = -L2E * lin_b[3 * HH + tid];

    // ---- stage x/2 and centres/2 (first 10 feats), padded rows of 12 ----
    for (int idx = tid; idx < TT * NQ; idx += 512) {
        int t = idx / NQ, qq = idx - t * NQ;
        xs[t * 12 + qq] = 0.5f * inputs[((size_t)t * BB + b) * DD + qq];
    }
    for (int idx = tid; idx < GC * NQ; idx += 512) {
        int gc = idx / NQ, qq = idx - gc * NQ;
        cs[gc * 12 + qq] = 0.5f * centres[(size_t)gc * DH + qq];
    }
    __syncthreads();

    // ---- Phase A: K[t][gc] -> LDS f16, vectorized row reads ----
    // thread covers gc quad gcq..gcq+3 for t = t0 + 16p (p=0..7)
    {
        const int gcq = (tid & 31) * 4;
        const int t0 = tid >> 5;
        #pragma unroll
        for (int p = 0; p < 8; ++p) {
            const int t = t0 + p * 16;
            const f4* xrow = (const f4*)&xs[t * 12];
            f4 x0 = xrow[0], x1 = xrow[1], x2 = xrow[2];
            float pv[4];
            #pragma unroll
            for (int u = 0; u < 4; ++u) {
                const f4* crow = (const f4*)&cs[(gcq + u) * 12];
                f4 cA = crow[0], cB = crow[1], cD = crow[2];
                float pr;
                pr  = fabsf(__cosf(x0.x - cA.x));
                pr *= fabsf(__cosf(x0.y - cA.y));
                pr *= fabsf(__cosf(x0.z - cA.z));
                pr *= fabsf(__cosf(x0.w - cA.w));
                pr *= fabsf(__cosf(x1.x - cB.x));
                pr *= fabsf(__cosf(x1.y - cB.y));
                pr *= fabsf(__cosf(x1.z - cB.z));
                pr *= fabsf(__cosf(x1.w - cB.w));
                pr *= fabsf(__cosf(x2.x - cD.x));
                pr *= fabsf(__cosf(x2.y - cD.y));
                pv[u] = pr;
            }
            h2 lo2 = __builtin_amdgcn_cvt_pkrtz(pv[0], pv[1]);
            h2 hi2 = __builtin_amdgcn_cvt_pkrtz(pv[2], pv[3]);
            h4 kk = { lo2.x, lo2.y, hi2.x, hi2.y };
            int byteo = (t * 256 + gcq * 2) ^ ((t & 7) << 4);
            *(h4*)((char*)Klds + byteo) = kk;
        }
    }
    __syncthreads();   // Klds complete; last barrier in the kernel

    // ---- per 8-t chunk: MFMA pre-activations, then recurrence.            ----
    // ---- preB is wave-private (cols [w*64,w*64+64)): NO block barriers.   ----
    float cstate = 0.f, hstate = 0.f;
    float* op = out + (size_t)b * HH + tid;
    const int tlo = c16 & 7;      // duplicated A rows: t = ct*8 + tlo
    const f4 z4 = {0.f, 0.f, 0.f, 0.f};
    // Klds read offsets: XOR must cover the FULL low byte (g*64 + q*16)
    // before any add — bit 6 of (tlo<<4) collides with g*64 otherwise.
    int aoff[4];
    #pragma unroll
    for (int g = 0; g < 4; ++g)
        aoff[g] = tlo * 256 + ((g * 64 + q * 16) ^ (tlo << 4));

    for (int ct = 0; ct < NCHUNK; ++ct) {
        const char* arp = (const char*)Klds + ct * 2048;
        h8 afr[4];
        #pragma unroll
        for (int g = 0; g < 4; ++g)
            afr[g] = *(const h8*)(arp + aoff[g]);

        #pragma unroll
        for (int j = 0; j < 4; ++j) {
            f4 a0 = __builtin_amdgcn_mfma_f32_16x16x32_f16(afr[0], bfr[0*4+j], z4, 0, 0, 0);
            f4 a1 = __builtin_amdgcn_mfma_f32_16x16x32_f16(afr[1], bfr[1*4+j], z4, 0, 0, 0);
            f4 a2 = __builtin_amdgcn_mfma_f32_16x16x32_f16(afr[2], bfr[2*4+j], z4, 0, 0, 0);
            f4 a3 = __builtin_amdgcn_mfma_f32_16x16x32_f16(afr[3], bfr[3*4+j], z4, 0, 0, 0);
            // D: col = c16 (h), row = q*4+r (t_local); rows 8-15 are dups, skip
            if (q < 2) {
                const int hcol = (w * 4 + j) * 16 + c16;
                #pragma unroll
                for (int r = 0; r < 4; ++r) {
                    const int tl = q * 4 + r;                 // 0..7
                    h2 p01 = __builtin_amdgcn_cvt_pkrtz(a0[r], a1[r]);
                    h2 p23 = __builtin_amdgcn_cvt_pkrtz(a2[r], a3[r]);
                    uint2 uu;
                    uu.x = *(unsigned*)&p01;
                    uu.y = *(unsigned*)&p23;
                    preB[tl * HH + hcol] = uu;
                }
            }
        }

        // recurrence: thread = h, 8 steps, 1 ds_read_b64 each (imm offsets).
        // Same-wave LDS ordering guarantees the writes above are visible.
        #pragma unroll
        for (int tl = 0; tl < CHUNK; ++tl) {
            uint2 vv = preB[tl * HH + tid];
            h2 vfi = *(h2*)&vv.x;
            h2 vgo = *(h2*)&vv.y;
            float yf = bias0 + (float)vfi.x;
            float yi = bias1 + (float)vfi.y;
            float yg = bias2 + (float)vgo.x;
            float yo = bias3 + (float)vgo.y;
            float fg = rcpf(1.f + exp2fast(yf));
            float ig = rcpf(1.f + exp2fast(yi));
            float og = rcpf(1.f + exp2fast(yo));
            float gg = 1.f - 2.f * rcpf(1.f + exp2fast(yg));
            cstate = fg * cstate + ig * gg;
            float th = 1.f - 2.f * rcpf(1.f + exp2fast((2.f * L2E) * cstate));
            hstate = og * th;
            op[(size_t)(ct * CHUNK + tl) * (BB * HH)] = hstate;
        }
    }

    float* hout = out + (size_t)TT * BB * HH;
    float* cout = hout + (size_t)BB * HH;
    hout[(size_t)b * HH + tid] = hstate;
    cout[(size_t)b * HH + tid] = cstate;
}

extern "C" void kernel_launch(void* const* d_in, const int* in_sizes, int n_in,
                              void* d_out, int out_size, void* d_ws, size_t ws_size,
                              hipStream_t stream) {
    const float* inputs  = (const float*)d_in[0];
    const float* centres = (const float*)d_in[1];
    const float* lin_w   = (const float*)d_in[2];
    const float* lin_b   = (const float*)d_in[3];
    float* out = (float*)d_out;

    qlstm_kernel<<<dim3(BB), dim3(512), 0, stream>>>(inputs, centres, lin_w, lin_b, out);
}